// Round 8
// baseline (151.280 us; speedup 1.0000x reference)
//
#include <hip/hip_runtime.h>
#include <hip/hip_bf16.h>
#include <stdint.h>

typedef unsigned short u16;
typedef unsigned int u32;
typedef __bf16 bf16x8 __attribute__((ext_vector_type(8)));
typedef _Float16 f16x8 __attribute__((ext_vector_type(8)));
typedef float f32x4 __attribute__((ext_vector_type(4)));

#define LOG2E 1.4426950408889634f

#define SBAR() do { __builtin_amdgcn_sched_barrier(0); __builtin_amdgcn_s_barrier(); __builtin_amdgcn_sched_barrier(0); } while (0)
#define VMW(n) do { asm volatile("s_waitcnt vmcnt(" #n ")" ::: "memory"); } while (0)

__device__ __forceinline__ u16 f2bf(float f) {
  u32 u = __builtin_bit_cast(u32, f);
  u += 0x7FFFu + ((u >> 16) & 1u);
  return (u16)(u >> 16);
}

__device__ __forceinline__ void gload_lds16(const void* g, void* l) {
  __builtin_amdgcn_global_load_lds(
      (const __attribute__((address_space(1))) u32*)g,
      (__attribute__((address_space(3))) u32*)l, 16, 0, 0);
}

// ---------------- convert / concat ----------------
__global__ void k_concat_bf16(const float* __restrict__ x, const float* __restrict__ y,
                              u16* __restrict__ xyb) {
  int tid = blockIdx.x * blockDim.x + threadIdx.x;
  int e = tid * 4;
  int s = e >> 9;
  int d = e & 511;
  int b = s >> 11, r = s & 2047;
  const float* src = (r < 1024) ? (x + ((size_t)(b * 1024 + r) * 512 + d))
                                : (y + ((size_t)(b * 1024 + (r - 1024)) * 512 + d));
  float4 v = *(const float4*)src;
  ushort4 o;
  o.x = f2bf(v.x); o.y = f2bf(v.y); o.z = f2bf(v.z); o.w = f2bf(v.w);
  *(ushort4*)(xyb + e) = o;
}

__global__ void k_w_to_bf16(const float* __restrict__ Wq, const float* __restrict__ Wk,
                            const float* __restrict__ Wv,
                            u16* __restrict__ Wqkb, u16* __restrict__ Wvb) {
  int tid = blockIdx.x * blockDim.x + threadIdx.x;  // 196608 threads
  int which = tid >> 16;
  int e = (tid & 65535) * 4;
  const float* src = (which == 0) ? Wq : (which == 1) ? Wk : Wv;
  u16* dst = (which == 0) ? Wqkb : (which == 1) ? (Wqkb + 262144) : Wvb;
  float4 v = *(const float4*)(src + e);
  ushort4 o;
  o.x = f2bf(v.x); o.y = f2bf(v.y); o.z = f2bf(v.z); o.w = f2bf(v.w);
  *(ushort4*)(dst + e) = o;
}

// ---------------- 8-phase GEMM: C = scale * A * B^T ----------------
// BM=256, BK=64, 8 waves. BN=256: waves 2x4, wave tile 128x64, 4 phases/tile.
// BN=128: waves 4x2, wave tile 64x64, 2 phases/tile. 16 MFMA per phase.
// LDS dbuf, rows 128B XOR-swizzled (pre-swizzled global_load_lds source).
// Staging is CHUNK-ordered to match phase consumption, so all in-loop waits
// are counted (vmcnt(4)/vmcnt(2)), never 0; each gate is followed by s_barrier
// so per-wave waits become collective. Two barriers per phase (m201 cadence).
// EXPSUM: C = exp(scale*acc) f16 + per-row partial sums -> lextra[row*ntiles+ty].
// DIVL:   C = scale*acc * lextra[z*2048+row] (f32 out), lextra = 1/l.
template <int BN, int ABF16, int OUTM, int EXPSUM, int DIVL>
__global__ __launch_bounds__(512, 2) void k_gemm8p(
    const u16* __restrict__ A, const u16* __restrict__ B, void* __restrict__ Cv,
    int lda, int ldb, int ldc,
    long long sA, long long sB, long long sC,
    int K, float scale, int batches, int mtiles, int ntiles,
    float* __restrict__ lextra) {
  constexpr int M_rep = (BN == 256) ? 8 : 4;
  constexpr int WN = (BN == 256) ? 4 : 2;
  constexpr int NA = (BN == 256) ? 4 : 2;   // A frags per read block
  constexpr int NB = (BN == 256) ? 2 : 4;   // B frags per read block
  constexpr int A_BYTES = 256 * 128;        // 32 KB
  constexpr int B_BYTES = BN * 128;         // 32 / 16 KB
  constexpr int BUFB = A_BYTES + B_BYTES;

  __shared__ __align__(16) char lds[2 * BUFB];

  int t = threadIdx.x, lane = t & 63, w = t >> 6;
  int wr = w / WN, wc = w % WN;

  int bid = blockIdx.x;
  long long z = bid % batches;
  int t2 = bid / batches;
  int tx = t2 % mtiles, ty = t2 / mtiles;

  size_t rsA = (size_t)lda * 2, rsB = (size_t)ldb * 2;
  int srow = t >> 3;
  int scb = ((t & 7) * 16) ^ ((srow & 7) << 4);  // pre-swizzled source byte col
  int dst16 = (t & 7) * 16;

  const char* Ab = (const char*)(A + z * sA + (size_t)tx * 256 * lda) + scb;
  const char* Bb = (const char*)(B + z * sB + (size_t)ty * BN * ldb) + scb;

  // chunk stagers; each = 2 gload_lds per thread; dest rows stay wave-contiguous
  auto stA = [&](int buf, int kt, int half) {
#pragma unroll
    for (int j = 0; j < 2; ++j) {
      int row;
      if constexpr (BN == 256) row = (j * 2 + half) * 64 + srow;           // quarters {0,2}/{1,3}
      else row = (j * 2 + (srow >> 5)) * 64 + half * 32 + (srow & 31);     // 32-row strips
      gload_lds16(Ab + (size_t)row * rsA + (size_t)kt * 128,
                  lds + buf * BUFB + row * 128 + dst16);
    }
  };
  auto stB = [&](int buf, int kt, int nh) {
#pragma unroll
    for (int j = 0; j < 2; ++j) {
      int row;
      if constexpr (BN == 256) row = (j * 2 + (srow >> 5)) * 64 + nh * 32 + (srow & 31);
      else row = j * 64 + srow;  // full B tile (nh unused)
      gload_lds16(Bb + (size_t)row * rsB + (size_t)kt * 128,
                  lds + buf * BUFB + A_BYTES + row * 128 + dst16);
    }
  };

  int axor = (lane & 7) << 4;
  int arow0 = wr * (M_rep * 16) + (lane & 15);
  int brow0 = wc * 64 + (lane & 15);
  int kb0 = (lane >> 4) * 16;

  bf16x8 afr[NA][2], bfr[NB][2];
  f32x4 acc[M_rep][4] = {};

  auto rdA = [&](const char* Ax, int mq) {
#pragma unroll
    for (int i = 0; i < NA; ++i)
#pragma unroll
      for (int kk = 0; kk < 2; ++kk)
        afr[i][kk] = *(const bf16x8*)(Ax + (arow0 + mq * (NA * 16) + i * 16) * 128 +
                                      ((kb0 + kk * 64) ^ axor));
  };
  auto rdB = [&](const char* Bx, int nq) {
#pragma unroll
    for (int j = 0; j < NB; ++j)
#pragma unroll
      for (int kk = 0; kk < 2; ++kk)
        bfr[j][kk] = *(const bf16x8*)(Bx + (brow0 + ((BN == 256) ? nq * 32 : 0) + j * 16) * 128 +
                                      ((kb0 + kk * 64) ^ axor));
  };
  auto mma = [&](int mq, int nq) {
    __builtin_amdgcn_s_setprio(1);
#pragma unroll
    for (int i = 0; i < NA; ++i)
#pragma unroll
      for (int j = 0; j < NB; ++j)
#pragma unroll
        for (int kk = 0; kk < 2; ++kk) {
          f32x4& a = acc[mq * NA + i][((BN == 256) ? nq * 2 : 0) + j];
          if constexpr (ABF16) {
            a = __builtin_amdgcn_mfma_f32_16x16x32_f16(
                __builtin_bit_cast(f16x8, afr[i][kk]), __builtin_bit_cast(f16x8, bfr[j][kk]),
                a, 0, 0, 0);
          } else {
            a = __builtin_amdgcn_mfma_f32_16x16x32_bf16(afr[i][kk], bfr[j][kk], a, 0, 0, 0);
          }
        }
    __builtin_amdgcn_s_setprio(0);
    __builtin_amdgcn_sched_barrier(0);
  };

  int NT = K >> 6;

  // prologue: stage tile 0 in consumption order
  if constexpr (BN == 256) { stA(0, 0, 0); stB(0, 0, 0); stB(0, 0, 1); stA(0, 0, 1); }
  else                     { stB(0, 0, 0); stA(0, 0, 0); stA(0, 0, 1); }

  for (int kt = 0; kt < NT; ++kt) {
    int buf = kt & 1, nbuf = buf ^ 1;
    bool stg = (kt + 1 < NT);
    const char* Ax = lds + buf * BUFB;
    const char* Bx = Ax + A_BYTES;

    if constexpr (BN == 256) {
      // Ph1 (mq0,nq0): gate on c0,c2 of this tile (allow c3,c1 in flight)
      VMW(4); SBAR();
      rdA(Ax, 0); rdB(Bx, 0); if (stg) stA(nbuf, kt + 1, 0);
      SBAR();
      mma(0, 0);
      // Ph2 (mq0,nq1): gate on c3
      if (stg) VMW(4); else VMW(2);
      SBAR();
      rdB(Bx, 1); if (stg) stB(nbuf, kt + 1, 0);
      SBAR();
      mma(0, 1);
      // Ph3 (mq1,nq0): gate on c1
      if (stg) VMW(4); else VMW(0);
      SBAR();
      rdA(Ax, 1); rdB(Bx, 0); if (stg) stB(nbuf, kt + 1, 1);
      SBAR();
      mma(1, 0);
      // Ph4 (mq1,nq1): no new chunk dep
      SBAR();
      rdB(Bx, 1); if (stg) stA(nbuf, kt + 1, 1);
      SBAR();
      mma(1, 1);
    } else {
      // Ph1 (mq0): gate on B + A-mq0 (allow A-mq1 in flight)
      VMW(2); SBAR();
      rdA(Ax, 0); rdB(Bx, 0);
      if (stg) { stB(nbuf, kt + 1, 0); stA(nbuf, kt + 1, 0); }
      SBAR();
      mma(0, 0);
      // Ph2 (mq1): gate on A-mq1
      if (stg) VMW(4); else VMW(0);
      SBAR();
      rdA(Ax, 1); if (stg) stA(nbuf, kt + 1, 1);
      SBAR();
      mma(1, 0);
    }
  }

  // ---------------- epilogue ----------------
  float* lds_l = (float*)lds;  // [256][WN] row-sum staging (EXPSUM only)
  if constexpr (EXPSUM) __syncthreads();

#pragma unroll
  for (int m = 0; m < M_rep; ++m) {
    int lrow = wr * (M_rep * 16) + m * 16 + ((lane >> 4) << 2);
    int grow = tx * 256 + lrow;
#pragma unroll
    for (int r = 0; r < 4; ++r) {
      float rs = 0.0f;
      float linv_v = 1.0f;
      if constexpr (DIVL) linv_v = lextra[z * 2048 + grow + r];
#pragma unroll
      for (int n = 0; n < 4; ++n) {
        int col = ty * BN + wc * 64 + n * 16 + (lane & 15);
        float v = acc[m][n][r] * scale;
        size_t idx = (size_t)(z * sC) + (size_t)(grow + r) * ldc + col;
        if constexpr (EXPSUM) {
          _Float16 h = (_Float16)exp2f(v * LOG2E);
          ((_Float16*)Cv)[idx] = h;
          rs += (float)h;  // sum rounded values so O/l is unbiased
        } else if constexpr (OUTM == 0) {
          ((u16*)Cv)[idx] = f2bf(v);
        } else if constexpr (OUTM == 1) {
          ((_Float16*)Cv)[idx] = (_Float16)v;
        } else {
          ((float*)Cv)[idx] = v * linv_v;
        }
      }
      if constexpr (EXPSUM) {
        rs += __shfl_xor(rs, 1, 16);
        rs += __shfl_xor(rs, 2, 16);
        rs += __shfl_xor(rs, 4, 16);
        rs += __shfl_xor(rs, 8, 16);
        if ((lane & 15) == 0) lds_l[(lrow + r) * WN + wc] = rs;
      }
    }
  }

  if constexpr (EXPSUM) {
    __syncthreads();
    if (t < 256) {
      float s = 0.0f;
#pragma unroll
      for (int q = 0; q < WN; ++q) s += lds_l[t * WN + q];
      lextra[(z * 2048 + tx * 256 + t) * ntiles + ty] = s;
    }
  }
}

// ---------------- invert row sums ----------------
__global__ __launch_bounds__(256) void k_inv_l(const float* __restrict__ lpart,
                                               float* __restrict__ linv,
                                               int mrows, int rowoff, int nparts) {
  int tid = blockIdx.x * blockDim.x + threadIdx.x;
  int z = tid / mrows, lr = tid - z * mrows;
  int row = z * 2048 + rowoff + lr;
  const float* p = lpart + (size_t)row * nparts;
  float s = 0.0f;
  for (int q = 0; q < nparts; ++q) s += p[q];
  linv[row] = 1.0f / s;
}

extern "C" void kernel_launch(void* const* d_in, const int* in_sizes, int n_in,
                              void* d_out, int out_size, void* d_ws, size_t ws_size,
                              hipStream_t stream) {
  const float* x = (const float*)d_in[0];
  const float* y = (const float*)d_in[1];
  const float* Wq = (const float*)d_in[2];
  const float* Wk = (const float*)d_in[3];
  const float* Wv = (const float*)d_in[4];
  float* out = (float*)d_out;

  char* p = (char*)d_ws;
  u16* QKb = (u16*)p; p += (size_t)16384 * 1024 * 2;  // Q cols 0-511, K cols 512-1023 (bf16)
  u16* VTh = (u16*)p; p += (size_t)16384 * 512 * 2;   // V^T f16 [512][16384]
  float* lpart = (float*)p; p += (size_t)16384 * 8 * 4;
  float* linv = (float*)p; p += (size_t)16384 * 4;
  u16* Wqkb = (u16*)p; p += (size_t)1024 * 512 * 2;   // [Wq;Wk]
  u16* Wvb = (u16*)p; p += (size_t)512 * 512 * 2;
  size_t base = (size_t)(p - (char*)d_ws);
  u16* xyb = (u16*)p;          // dead after VT projection
  _Float16* Sb = (_Float16*)p; // aliases xyb

  int nc = (ws_size >= base + (size_t)16384 * 2048 * 2) ? 1 : 2;
  int mrows = 2048 / nc;
  int mt = mrows / 256;

  // converts
  k_concat_bf16<<<8192, 256, 0, stream>>>(x, y, xyb);
  k_w_to_bf16<<<768, 256, 0, stream>>>(Wq, Wk, Wv, Wqkb, Wvb);

  // fused Q/K projection: [16384][1024] = xy @ [Wq;Wk]^T (bf16 out)
  k_gemm8p<256, 0, 0, 0, 0><<<256, 512, 0, stream>>>(
      xyb, Wqkb, QKb, 512, 512, 1024, 0, 0, 0, 512, 1.0f, 1, 64, 4, nullptr);
  // VT projection: [512][16384] = Wv @ xy^T (f16 out)
  k_gemm8p<128, 0, 1, 0, 0><<<256, 512, 0, stream>>>(
      Wvb, xyb, VTh, 512, 512, 16384, 0, 0, 0, 512, 1.0f, 1, 2, 128, nullptr);

  const float scale = 0.044194173824159216f;  // 1/sqrt(512)
  for (int c = 0; c < nc; ++c) {
    const u16* Qc = QKb + (size_t)c * mrows * 1024;
    // P = exp(scale * Q K^T) (f16 out) + row partial sums -> lpart
    k_gemm8p<256, 0, 1, 1, 0><<<8 * mt * 8, 512, 0, stream>>>(
        Qc, QKb + 512, Sb, 1024, 1024, 2048,
        (long long)2048 * 1024, (long long)2048 * 1024, (long long)mrows * 2048,
        512, scale, 8, mt, 8, lpart + (size_t)c * mrows * 8);
    // linv = 1 / rowsum
    k_inv_l<<<(8 * mrows) / 256, 256, 0, stream>>>(lpart, linv, mrows, c * mrows, 8);
    // O = (P @ VT^T) * linv (f16 in, f32 out)
    k_gemm8p<128, 1, 2, 0, 1><<<8 * mt * 4, 512, 0, stream>>>(
        (const u16*)Sb, VTh, out + (size_t)c * mrows * 512, 2048, 16384, 512,
        (long long)mrows * 2048, (long long)2048, (long long)2048 * 512,
        2048, 1.0f, 8, mt, 4, linv + (size_t)c * mrows);
  }
}